// Round 15
// baseline (669.918 us; speedup 1.0000x reference)
//
#include <hip/hip_runtime.h>
#include <hip/hip_bf16.h>
#include <math.h>

#define N_PTS 16384
#define NLAYER 4

typedef __attribute__((ext_vector_type(8))) short bfrag;
typedef __attribute__((ext_vector_type(4))) float f32x4;
typedef unsigned short ushort_t;
typedef unsigned int uint_t;

__device__ __forceinline__ ushort_t f2b(float f) {
  __hip_bfloat16 h = __float2bfloat16(f);
  return *reinterpret_cast<const ushort_t*>(&h);
}
__device__ __forceinline__ float b2f(ushort_t u) {
  union { uint_t i; float f; } c; c.i = ((uint_t)u) << 16; return c.f;
}
__device__ __forceinline__ float blo(uint_t u) {
  union { uint_t i; float f; } c; c.i = u << 16; return c.f;
}
__device__ __forceinline__ float bhi(uint_t u) {
  union { uint_t i; float f; } c; c.i = u & 0xffff0000u; return c.f;
}

// async global->LDS, 16B/lane; LDS dest wave-uniform; HW adds lane*16.
__device__ __forceinline__ void gload16(const ushort_t* g, ushort_t* l) {
  __builtin_amdgcn_global_load_lds(
      (const __attribute__((address_space(1))) unsigned int*)g,
      (__attribute__((address_space(3))) unsigned int*)l, 16, 0, 0);
}

#define MFMA16(a, b, c) __builtin_amdgcn_mfma_f32_16x16x32_bf16((a), (b), (c), 0, 0, 0)
#define WVM5() asm volatile("s_waitcnt vmcnt(5)" ::: "memory")
#define WVM0() asm volatile("s_waitcnt vmcnt(0)" ::: "memory")

// ---------------------------------------------------------------------------
__global__ __launch_bounds__(256) void base_kernel(
    const float* __restrict__ enc, const float* __restrict__ W_in,
    const float* __restrict__ b_in, float* __restrict__ base)
{
  int b = blockIdx.x, j = threadIdx.x;
  __shared__ float se[256];
  se[j] = enc[b * 256 + j];
  __syncthreads();
  float acc = b_in[j] + W_in[j];
  for (int i = 1; i < 256; ++i) acc += se[i] * W_in[i * 256 + j];
  base[b * 256 + j] = acc;
}

// h row-major bf16 + fragment-order hbP
__global__ __launch_bounds__(256) void embed_kernel(
    const float* __restrict__ base, const int* __restrict__ batch_idx,
    const float* __restrict__ pos, const float* __restrict__ W_in,
    ushort_t* __restrict__ h_bf, ushort_t* __restrict__ hbP)
{
  int n = blockIdx.x, j = threadIdx.x;
  int b = batch_idx[n];
  float px = pos[n * 3 + 0], py = pos[n * 3 + 1], pz = pos[n * 3 + 2];
  float v = base[b * 256 + j]
      + px * W_in[256 * 256 + j] + py * W_in[257 * 256 + j] + pz * W_in[258 * 256 + j];
  ushort_t u = f2b(v);
  h_bf[(size_t)n * 256 + j] = u;
  int rt = n >> 4, ct = j >> 4;
  int lane = ((n & 15) >> 2) * 16 + (j & 15);
  hbP[(((size_t)rt * 16 + ct) * 64 + lane) * 4 + (n & 3)] = u;
}

// ---------------------------------------------------------------------------
// W3P (qkv): block (ct*8+ks), 1KB fragment blocks
__global__ __launch_bounds__(256) void prep_qkv(
    const float* __restrict__ Wq, const float* __restrict__ Wk,
    const float* __restrict__ Wv, const float* __restrict__ We,
    ushort_t* __restrict__ out)
{
  int idx = blockIdx.x * 256 + threadIdx.x;  // < 4*640*256
  int l = idx / (640 * 256);
  int rem = idx - l * (640 * 256);
  int c = rem >> 8, k = rem & 255;
  float v = 0.f;
  if (c < 128) v = Wq[((size_t)l * 256 + k) * 128 + c];
  else if (c < 328) {
    int p = c - 128, hq = p / 50, r = p - hq * 50;
    const float* wq = &Wq[((size_t)l * 256 + k) * 128 + hq * 32];
    const float* we = &We[((size_t)l * 50 + r) * 128 + hq * 32];
#pragma unroll
    for (int d = 0; d < 32; ++d) v += wq[d] * we[d];
  } else if (c < 456) v = Wk[((size_t)l * 256 + k) * 128 + (c - 328)];
  else if (c < 584) v = Wv[((size_t)l * 256 + k) * 128 + (c - 456)];
  size_t pos = (size_t)l * 163840
      + (((c >> 4) * 8 + (k >> 5)) * 64 + ((k >> 3) & 3) * 16 + (c & 15)) * 8 + (k & 7);
  out[pos] = f2b(v);
}

// BcP: block (ks*16+ct), K=352
__global__ __launch_bounds__(256) void prep_bcat(
    const float* __restrict__ We, const float* __restrict__ Wo, ushort_t* __restrict__ out)
{
  int idx = blockIdx.x * 256 + threadIdx.x;  // < 4*256*352
  if (idx >= 4 * 256 * 352) return;
  int l = idx / (256 * 352);
  int rem = idx - l * (256 * 352);
  int c = rem / 352, k = rem - c * 352;
  float v = 0.f;
  if (k < 128) v = Wo[((size_t)l * 128 + k) * 256 + c];
  else if (k < 328) {
    int p = k - 128, hq = p / 50, r = p - hq * 50;
    const float* we = &We[((size_t)l * 50 + r) * 128 + hq * 32];
    const float* wo = &Wo[((size_t)l * 128 + hq * 32) * 256 + c];
#pragma unroll
    for (int d = 0; d < 32; ++d) v += we[d] * wo[(size_t)d * 256];
  }
  size_t pos = (size_t)l * 90112
      + (((k >> 5) * 16 + (c >> 4)) * 64 + ((k >> 3) & 3) * 16 + (c & 15)) * 8 + (k & 7);
  out[pos] = f2b(v);
}

// WfP: block (ks*16+ct)
__global__ __launch_bounds__(256) void prep_wfc(
    const float* __restrict__ Wfc, ushort_t* __restrict__ out)
{
  int idx = blockIdx.x * 256 + threadIdx.x;  // < 4*256*256
  int l = idx >> 16, rem = idx & 65535;
  int c = rem >> 8, k = rem & 255;
  float v = Wfc[((size_t)l * 256 + k) * 256 + c];
  size_t pos = (size_t)l * 65536
      + (((k >> 5) * 16 + (c >> 4)) * 64 + ((k >> 3) & 3) * 16 + (c & 15)) * 8 + (k & 7);
  out[pos] = f2b(v);
}

// WoP: block (ct*8+ks), cols padded to 128
__global__ __launch_bounds__(256) void prep_wout(
    const float* __restrict__ W_out, ushort_t* __restrict__ out)
{
  int idx = blockIdx.x * 256 + threadIdx.x;  // < 128*256
  int c = idx >> 8, k = idx & 255;
  float v = (c < 103) ? W_out[(size_t)k * 103 + c] : 0.f;
  size_t pos = (((c >> 4) * 8 + (k >> 5)) * 64 + ((k >> 3) & 3) * 16 + (c & 15)) * 8 + (k & 7);
  out[pos] = f2b(v);
}

// ---------------------------------------------------------------------------
// Fused layer v9: per-wave async B-stream. 512 blocks x 256 thr (4 waves),
// 32 rows/block (2 row-tiles); wave owns a column quarter. Each wave streams
// 1KB B-fragments via global_load_lds into a private 8-slot LDS ring with
// counted per-wave vmcnt(5) — ZERO barriers in GEMM loops.
// MODE 0: full layer -> qkv. MODE 1: full layer -> out. MODE 2: qkv only.
template<int MODE>
__global__ __launch_bounds__(256) void fused_layer(
    const ushort_t* __restrict__ Amsg,  // [N][352] (MODE!=2)
    const ushort_t* __restrict__ BcP,   // packed, block (ks*16+ct), ks<11
    const float* __restrict__ bo,
    ushort_t* __restrict__ hbP,         // fragment-order residual stream
    const float* __restrict__ lg, const float* __restrict__ lb,
    const ushort_t* __restrict__ WfP,   // packed, block (ks*16+ct), ks<8
    const float* __restrict__ bfc,
    const ushort_t* __restrict__ W3P,   // packed, block (ct*8+ks); 40 or 8 ct
    const float* __restrict__ b3,
    const ushort_t* __restrict__ h_bf,  // row-major h (MODE 2)
    ushort_t* __restrict__ qext_b, ushort_t* __restrict__ kvb,
    float* __restrict__ outF)
{
  __shared__ __align__(16) ushort_t sA[32 * 384];   // A (G1); then gelu (ld 256)
  __shared__ __align__(16) ushort_t sH[32 * 256];   // hln (ld 256, swizzled)
  __shared__ __align__(16) ushort_t ring[4 * 8 * 512];  // 4 waves x 8 x 1KB
  __shared__ float pS[4][32], pSS[4][32];

  const int tid = threadIdx.x;
  const int lane = tid & 63, wv = tid >> 6;
  const int l15 = lane & 15, l4 = lane >> 4;
  const int r7 = l15 & 7;
  const int r0 = blockIdx.x * 32;
  const int rtg = blockIdx.x * 2;          // global row-tile base
  ushort_t* ring_w = ring + wv * (8 * 512);
  const int loff = lane * 8;               // lane's 16B offset in a 1KB block

  if constexpr (MODE != 2) {
    // ---- stage Amsg tile -> sA [32][384], XOR-swizzled, zero K-pad
    for (int i = tid; i < 32 * 48; i += 256) {
      int r = i / 48, c8 = i - r * 48;
      uint4 v = (uint4){0, 0, 0, 0};
      if (c8 < 44) v = *(const uint4*)(Amsg + (size_t)(r0 + r) * 352 + c8 * 8);
      *(uint4*)(&sA[r * 384 + ((c8 ^ (r & 7)) << 3)]) = v;
    }
    __syncthreads();

    const int cb = wv * 4;   // ct base for G1/G2 (4 of 16)

    // ================= GEMM1: K=352, 44 stream-iters =================
    f32x4 acc[2][4];
#pragma unroll
    for (int m = 0; m < 2; ++m)
#pragma unroll
      for (int j = 0; j < 4; ++j) acc[m][j] = (f32x4){0.f, 0.f, 0.f, 0.f};
#pragma unroll
    for (int p = 0; p < 6; ++p) {
      int blk = (p >> 2) * 16 + cb + (p & 3);
      gload16(BcP + (size_t)blk * 512 + loff, ring_w + (p & 7) * 512);
    }
    {
      bfrag a0, a1;
      for (int i = 0; i < 44; ++i) {
        WVM5();
        const int ks = i >> 2, j = i & 3;
        bfrag b = *(const bfrag*)(ring_w + (i & 7) * 512 + loff);
        if (j == 0) {
          const int ch = ks * 4 + l4;
          a0 = *(const bfrag*)(sA + l15 * 384 + ((ch ^ r7) << 3));
          a1 = *(const bfrag*)(sA + (16 + l15) * 384 + ((ch ^ r7) << 3));
        }
        __builtin_amdgcn_s_setprio(1);
        acc[0][j] = MFMA16(a0, b, acc[0][j]);
        acc[1][j] = MFMA16(a1, b, acc[1][j]);
        __builtin_amdgcn_s_setprio(0);
        int pn = i + 6; if (pn > 43) pn = 43;
        int blkn = (pn >> 2) * 16 + cb + (pn & 3);
        gload16(BcP + (size_t)blkn * 512 + loff, ring_w + ((i + 6) & 7) * 512);
      }
      WVM0();
    }

    // ---- epilogue 1: + bo + resid(hbP), partial LN stats
#pragma unroll
    for (int m = 0; m < 2; ++m)
#pragma unroll
      for (int i = 0; i < 4; ++i) {
        const int rl = m * 16 + l4 * 4 + i;
        float s = 0.f, q = 0.f;
#pragma unroll
        for (int j = 0; j < 4; ++j) {
          const int c = (cb + j) * 16 + l15;
          // load resid element (frag-order)
          float hv = b2f(hbP[(((size_t)(rtg + m) * 16 + cb + j) * 64 + lane) * 4 + i]);
          float x = acc[m][j][i] + bo[c] + hv;
          acc[m][j][i] = x;
          s += x; q += x * x;
        }
#pragma unroll
        for (int off = 1; off < 16; off <<= 1) {
          s += __shfl_xor(s, off, 64);
          q += __shfl_xor(q, off, 64);
        }
        if (l15 == 0) { pS[wv][rl] = s; pSS[wv][rl] = q; }
      }
    __syncthreads();
    // ---- LN -> sH (ld 256, swizzled)
#pragma unroll
    for (int m = 0; m < 2; ++m)
#pragma unroll
      for (int i = 0; i < 4; ++i) {
        const int rl = m * 16 + l4 * 4 + i;
        float S = pS[0][rl] + pS[1][rl] + pS[2][rl] + pS[3][rl];
        float Q = pSS[0][rl] + pSS[1][rl] + pSS[2][rl] + pSS[3][rl];
        float mu = S * (1.f / 256.f);
        float var = Q * (1.f / 256.f) - mu * mu;
        float inv = 1.0f / sqrtf(var + 1e-5f);
#pragma unroll
        for (int j = 0; j < 4; ++j) {
          const int c = (cb + j) * 16 + l15;
          sH[rl * 256 + ((((c >> 3) ^ (rl & 7)) << 3) | (c & 7))] =
              f2b(lg[c] * (acc[m][j][i] - mu) * inv + lb[c]);
        }
      }
    __syncthreads();

    // ================= GEMM2: K=256, 32 stream-iters =================
#pragma unroll
    for (int m = 0; m < 2; ++m)
#pragma unroll
      for (int j = 0; j < 4; ++j) acc[m][j] = (f32x4){0.f, 0.f, 0.f, 0.f};
#pragma unroll
    for (int p = 0; p < 6; ++p) {
      int blk = (p >> 2) * 16 + cb + (p & 3);
      gload16(WfP + (size_t)blk * 512 + loff, ring_w + (p & 7) * 512);
    }
    {
      bfrag a0, a1;
      for (int i = 0; i < 32; ++i) {
        WVM5();
        const int ks = i >> 2, j = i & 3;
        bfrag b = *(const bfrag*)(ring_w + (i & 7) * 512 + loff);
        if (j == 0) {
          const int ch = ks * 4 + l4;
          a0 = *(const bfrag*)(sH + l15 * 256 + ((ch ^ r7) << 3));
          a1 = *(const bfrag*)(sH + (16 + l15) * 256 + ((ch ^ r7) << 3));
        }
        __builtin_amdgcn_s_setprio(1);
        acc[0][j] = MFMA16(a0, b, acc[0][j]);
        acc[1][j] = MFMA16(a1, b, acc[1][j]);
        __builtin_amdgcn_s_setprio(0);
        int pn = i + 6; if (pn > 31) pn = 31;
        int blkn = (pn >> 2) * 16 + cb + (pn & 3);
        gload16(WfP + (size_t)blkn * 512 + loff, ring_w + ((i + 6) & 7) * 512);
      }
      WVM0();
    }

    // ---- epilogue 2: gelu -> hbP (frag-order) + sA (ld 256, swizzled)
#pragma unroll
    for (int m = 0; m < 2; ++m)
#pragma unroll
      for (int j = 0; j < 4; ++j) {
        const int c = (cb + j) * 16 + l15;
        const float bfcc = bfc[c];
        ushort_t uo[4];
#pragma unroll
        for (int i = 0; i < 4; ++i) {
          const int rl = m * 16 + l4 * 4 + i;
          float x = acc[m][j][i] + bfcc;
          float t = tanhf(0.7978845608028654f * (x + 0.044715f * x * x * x));
          float gl = 0.5f * x * (1.f + t);
          uo[i] = f2b(gl);
          sA[rl * 256 + ((((c >> 3) ^ (rl & 7)) << 3) | (c & 7))] = uo[i];
        }
        *(uint2*)(hbP + (((size_t)(rtg + m) * 16 + cb + j) * 64 + lane) * 4) =
            *(const uint2*)uo;
      }
    __syncthreads();
  } else {
    // MODE 2: stage h_bf tile -> sA (ld 256, swizzled)
    for (int i = tid; i < 32 * 32; i += 256) {
      int r = i >> 5, c8 = i & 31;
      *(uint4*)(&sA[r * 256 + ((c8 ^ (r & 7)) << 3)]) =
          *(const uint4*)(h_bf + (size_t)(r0 + r) * 256 + c8 * 8);
    }
    __syncthreads();
  }

  // ================= GEMM3: K=256, ct chunks, per-wave stream =============
  {
    constexpr int CTC = (MODE == 1) ? 2 : 5;     // ct per chunk
    constexpr int NCH = (MODE == 1) ? 1 : 2;     // chunks
    constexpr int NPC = 8 * CTC;                 // iters per chunk
    constexpr int NI3 = NCH * NPC;
    const int cg = wv * (CTC * NCH);
#pragma unroll
    for (int p = 0; p < 6; ++p) {
      int ks = p / CTC, j = p - ks * CTC;        // p < NPC always (NPC>=16)
      int blk = (cg + j) * 8 + ks;
      gload16(W3P + (size_t)blk * 512 + loff, ring_w + (p & 7) * 512);
    }
    f32x4 a3[2][CTC];
    bfrag a0, a1;
    for (int i = 0; i < NI3; ++i) {
      const int chunk = i / NPC;
      const int rr = i - chunk * NPC;
      const int ks = rr / CTC, j = rr - ks * CTC;
      if (rr == 0) {
#pragma unroll
        for (int m = 0; m < 2; ++m)
#pragma unroll
          for (int t = 0; t < CTC; ++t) a3[m][t] = (f32x4){0.f, 0.f, 0.f, 0.f};
      }
      WVM5();
      bfrag b = *(const bfrag*)(ring_w + (i & 7) * 512 + loff);
      if (j == 0) {
        const int ch = ks * 4 + l4;
        a0 = *(const bfrag*)(sA + l15 * 256 + ((ch ^ r7) << 3));
        a1 = *(const bfrag*)(sA + (16 + l15) * 256 + ((ch ^ r7) << 3));
      }
      __builtin_amdgcn_s_setprio(1);
      a3[0][j] = MFMA16(a0, b, a3[0][j]);
      a3[1][j] = MFMA16(a1, b, a3[1][j]);
      __builtin_amdgcn_s_setprio(0);
      if (rr == NPC - 1) {
        const int ctb = cg + chunk * CTC;
#pragma unroll
        for (int t = 0; t < CTC; ++t) {
          const int c = (ctb + t) * 16 + l15;
#pragma unroll
          for (int m = 0; m < 2; ++m)
#pragma unroll
            for (int i2 = 0; i2 < 4; ++i2) {
              const size_t r = (size_t)(r0 + m * 16 + l4 * 4 + i2);
              float v = a3[m][t][i2];
              if constexpr (MODE == 1) {
                if (c < 103) outF[r * 103 + c] = v + b3[c];
              } else {
                if (c < 328) qext_b[r * 352 + c] = f2b(v);
                else if (c < 584) kvb[r * 256 + (c - 328)] = f2b(v);
              }
            }
        }
      }
      int pn = i + 6; if (pn > NI3 - 1) pn = NI3 - 1;
      const int pch = pn / NPC;
      const int prr = pn - pch * NPC;
      const int pks = prr / CTC, pj = prr - pks * CTC;
      int blkn = (cg + pch * CTC + pj) * 8 + pks;
      gload16(W3P + (size_t)blkn * 512 + loff, ring_w + ((i + 6) & 7) * 512);
    }
    WVM0();
  }
}

// ---------------------------------------------------------------------------
// Attention: K/V straight from L2, all LDS per-wave, no block barriers.
__global__ __launch_bounds__(256) void attn_kernel(
    const ushort_t* __restrict__ qext, const ushort_t* __restrict__ kvb,
    const float* __restrict__ pos, const int* __restrict__ nbrs,
    const float* __restrict__ mask, ushort_t* __restrict__ Amsg)
{
  __shared__ __align__(16) ushort_t sQ[4][128];
  __shared__ __align__(16) float    sQE[4][4][52];
  __shared__ __align__(16) ushort_t sRbf[4][16][52];
  __shared__ float sA[4][64];
  __shared__ float sD[4][16];
  __shared__ float sMk[4][16];
  __shared__ int   sNb[4][16];

  const int tid = threadIdx.x;
  const int bid = blockIdx.x;
  const int lane = tid & 63, w = tid >> 6;
  const int g = (bid & 7) + 8 * ((bid >> 3) & 15);
  const int q4 = bid >> 7;
  const int kk = lane >> 2, hh = lane & 3;

  for (int it = 0; it < 4; ++it) {
    const int n = g * 128 + q4 * 16 + w * 4 + it;
    if (lane < 16) {
      int nb = nbrs[n * 16 + lane];
      sNb[w][lane] = nb;
      sMk[w][lane] = mask[n * 16 + lane];
      float dx = pos[nb * 3 + 0] - pos[n * 3 + 0];
      float dy = pos[nb * 3 + 1] - pos[n * 3 + 1];
      float dz = pos[nb * 3 + 2] - pos[n * 3 + 2];
      sD[w][lane] = sqrtf(dx * dx + dy * dy + dz * dz + 1e-12f);
      sRbf[w][lane][50] = 0; sRbf[w][lane][51] = 0;
      *(uint4*)(&sQ[w][lane * 8]) = *(const uint4*)(qext + (size_t)n * 352 + lane * 8);
    }
    if (lane < 50) {
      uint2 u = *(const uint2*)(qext + (size_t)n * 352 + 128 + lane * 4);
      int p = lane * 4;
#pragma unroll
      for (int e = 0; e < 4; ++e) {
        ushort_t bb = ((const ushort_t*)&u)[e];
        int pp = p + e, h2 = pp / 50, r = pp - h2 * 50;
        sQE[w][h2][r] = b2f(bb);
      }
    }
    if (lane < 8) sQE[w][lane >> 1][50 + (lane & 1)] = 0.f;
    {
      int kk2 = lane & 15;
      float dk = sD[w][kk2];
      int r0 = lane >> 4;
#pragma unroll
      for (int j = 0; j < 13; ++j) {
        int r = r0 + j * 4;
        if (r < 50) {
          float t = (dk - (2.f / 49.f) * (float)r) * 24.5f;
          sRbf[w][kk2][r] = f2b(__expf(-0.5f * t * t));
        }
      }
    }
    const int nb = sNb[w][kk];
    const ushort_t* krow = kvb + (size_t)nb * 256 + hh * 32;
    float qk = 0.f;
#pragma unroll
    for (int c8 = 0; c8 < 4; ++c8) {
      uint4 kv4 = *(const uint4*)(krow + c8 * 8);
      const uint_t* q4p = (const uint_t*)(&sQ[w][hh * 32 + c8 * 8]);
      uint_t qa = q4p[0], qb = q4p[1], qc = q4p[2], qd = q4p[3];
      qk += blo(qa) * blo(kv4.x) + bhi(qa) * bhi(kv4.x)
          + blo(qb) * blo(kv4.y) + bhi(qb) * bhi(kv4.y)
          + blo(qc) * blo(kv4.z) + bhi(qc) * bhi(kv4.z)
          + blo(qd) * blo(kv4.w) + bhi(qd) * bhi(kv4.w);
    }
    float qe = 0.f;
#pragma unroll
    for (int c = 0; c < 13; ++c) {
      float4 qv = *(const float4*)(&sQE[w][hh][c * 4]);
      uint2 rv = *(const uint2*)(&sRbf[w][kk][c * 4]);
      qe += qv.x * blo(rv.x) + qv.y * bhi(rv.x)
          + qv.z * blo(rv.y) + qv.w * bhi(rv.y);
    }
    float lg = 0.17677669529663687f * (qk + qe);
    lg = (sMk[w][kk] > 0.f) ? lg : -1e9f;

    float mx = lg;
#pragma unroll
    for (int off = 4; off < 64; off <<= 1) mx = fmaxf(mx, __shfl_xor(mx, off, 64));
    float ex = __expf(lg - mx);
    float sm = ex;
#pragma unroll
    for (int off = 4; off < 64; off <<= 1) sm += __shfl_xor(sm, off, 64);
    sA[w][kk * 4 + hh] = ex / sm * sMk[w][kk];

    if (lane < 50) {
      float r0 = 0.f, r1 = 0.f, r2 = 0.f, r3 = 0.f;
#pragma unroll
      for (int k2 = 0; k2 < 16; ++k2) {
        float rb = b2f(sRbf[w][k2][lane]);
        r0 += sA[w][k2 * 4 + 0] * rb;
        r1 += sA[w][k2 * 4 + 1] * rb;
        r2 += sA[w][k2 * 4 + 2] * rb;
        r3 += sA[w][k2 * 4 + 3] * rb;
      }
      Amsg[(size_t)n * 352 + 128 + 0 * 50 + lane] = f2b(r0);
      Amsg[(size_t)n * 352 + 128 + 1 * 50 + lane] = f2b(r1);
      Amsg[(size_t)n * 352 + 128 + 2 * 50 + lane] = f2b(r2);
      Amsg[(size_t)n * 352 + 128 + 3 * 50 + lane] = f2b(r3);
    }
    {
      const int h2 = lane >> 4;
      float m0v = 0.f, m1v = 0.f;
#pragma unroll
      for (int k2 = 0; k2 < 16; ++k2) {
        int nb2 = sNb[w][k2];
        uint_t vv = *(const uint_t*)(kvb + (size_t)nb2 * 256 + 128 + lane * 2);
        float a = sA[w][k2 * 4 + h2];
        m0v += a * blo(vv);
        m1v += a * bhi(vv);
      }
      uint_t o = (uint_t)f2b(m0v) | ((uint_t)f2b(m1v) << 16);
      *(uint_t*)(&Amsg[(size_t)n * 352 + lane * 2]) = o;
    }
    if (lane < 24) Amsg[(size_t)n * 352 + 328 + lane] = 0;
  }
}

// ---------------------------------------------------------------------------
extern "C" void kernel_launch(void* const* d_in, const int* in_sizes, int n_in,
                              void* d_out, int out_size, void* d_ws, size_t ws_size,
                              hipStream_t stream) {
  const float* enc    = (const float*)d_in[0];
  const float* pos    = (const float*)d_in[1];
  const int*   bidx   = (const int*)  d_in[2];
  const int*   nbrs   = (const int*)  d_in[3];
  const float* mask   = (const float*)d_in[4];
  const float* W_in   = (const float*)d_in[5];
  const float* b_in   = (const float*)d_in[6];
  const float* Wq     = (const float*)d_in[7];
  const float* Wk     = (const float*)d_in[8];
  const float* Wv     = (const float*)d_in[9];
  const float* We     = (const float*)d_in[10];
  const float* Wo     = (const float*)d_in[11];
  const float* bo     = (const float*)d_in[12];
  const float* Wfc    = (const float*)d_in[13];
  const float* bfc    = (const float*)d_in[14];
  const float* ln_g   = (const float*)d_in[15];
  const float* ln_b   = (const float*)d_in[16];
  const float* W_out  = (const float*)d_in[17];
  const float* b_out  = (const float*)d_in[18];
  float* out = (float*)d_out;

  const int N = N_PTS;
  ushort_t* ws = (ushort_t*)d_ws;
  ushort_t* hbP    = ws;                                  // N*256 frag-order
  ushort_t* h_bf   = hbP + (size_t)N * 256;               // N*256 row-major
  ushort_t* qext_b = h_bf + (size_t)N * 256;              // N*352
  ushort_t* kvb    = qext_b + (size_t)N * 352;            // N*256
  ushort_t* Amsg   = kvb + (size_t)N * 256;               // N*352
  float*    base   = (float*)(Amsg + (size_t)N * 352);    // 128*256 fp32
  ushort_t* W3P    = (ushort_t*)(base + 128 * 256);       // 4*163840
  ushort_t* BcP    = W3P + 4 * 163840;                    // 4*90112
  ushort_t* WfP    = BcP + 4 * 90112;                     // 4*65536
  ushort_t* WoP    = WfP + 4 * 65536;                     // 32768

  base_kernel<<<128, 256, 0, stream>>>(enc, W_in, b_in, base);
  embed_kernel<<<N, 256, 0, stream>>>(base, bidx, pos, W_in, h_bf, hbP);
  prep_qkv<<<(4 * 640 * 256) / 256, 256, 0, stream>>>(Wq, Wk, Wv, We, W3P);
  prep_bcat<<<(4 * 256 * 352 + 255) / 256, 256, 0, stream>>>(We, Wo, BcP);
  prep_wfc<<<(4 * 256 * 256) / 256, 256, 0, stream>>>(Wfc, WfP);
  prep_wout<<<(128 * 256) / 256, 256, 0, stream>>>(W_out, WoP);

  // layer-0 qkv from embedded features
  fused_layer<2><<<N / 32, 256, 0, stream>>>(
      nullptr, nullptr, nullptr, nullptr, nullptr, nullptr, nullptr, nullptr,
      W3P, nullptr, h_bf, qext_b, kvb, nullptr);

  for (int l = 0; l < NLAYER; ++l) {
    const ushort_t* BcP_l = BcP + (size_t)l * 90112;
    const ushort_t* WfP_l = WfP + (size_t)l * 65536;
    const float* bo_l  = bo  + (size_t)l * 256;
    const float* bfc_l = bfc + (size_t)l * 256;
    const float* lg_l  = ln_g + (size_t)l * 256;
    const float* lb_l  = ln_b + (size_t)l * 256;

    attn_kernel<<<1024, 256, 0, stream>>>(qext_b, kvb, pos, nbrs, mask, Amsg);

    if (l < NLAYER - 1) {
      const ushort_t* W3P_next = W3P + (size_t)(l + 1) * 163840;
      fused_layer<0><<<N / 32, 256, 0, stream>>>(
          Amsg, BcP_l, bo_l, hbP, lg_l, lb_l, WfP_l, bfc_l,
          W3P_next, nullptr, nullptr, qext_b, kvb, nullptr);
    } else {
      fused_layer<1><<<N / 32, 256, 0, stream>>>(
          Amsg, BcP_l, bo_l, hbP, lg_l, lb_l, WfP_l, bfc_l,
          WoP, b_out, nullptr, nullptr, nullptr, out);
    }
  }
}

// Round 16
// 666.002 us; speedup vs baseline: 1.0059x; 1.0059x over previous
//
#include <hip/hip_runtime.h>
#include <hip/hip_bf16.h>
#include <math.h>

#define N_PTS 16384
#define NLAYER 4

typedef __attribute__((ext_vector_type(8))) short bfrag;
typedef __attribute__((ext_vector_type(4))) float f32x4;
typedef unsigned short ushort_t;
typedef unsigned int uint_t;

__device__ __forceinline__ ushort_t f2b(float f) {
  __hip_bfloat16 h = __float2bfloat16(f);
  return *reinterpret_cast<const ushort_t*>(&h);
}
__device__ __forceinline__ float b2f(ushort_t u) {
  union { uint_t i; float f; } c; c.i = ((uint_t)u) << 16; return c.f;
}
__device__ __forceinline__ float blo(uint_t u) {
  union { uint_t i; float f; } c; c.i = u << 16; return c.f;
}
__device__ __forceinline__ float bhi(uint_t u) {
  union { uint_t i; float f; } c; c.i = u & 0xffff0000u; return c.f;
}

// async global->LDS, 16B/lane; LDS dest wave-uniform; HW adds lane*16.
__device__ __forceinline__ void gload16(const ushort_t* g, ushort_t* l) {
  __builtin_amdgcn_global_load_lds(
      (const __attribute__((address_space(1))) unsigned int*)g,
      (__attribute__((address_space(3))) unsigned int*)l, 16, 0, 0);
}

#define MFMA16(a, b, c) __builtin_amdgcn_mfma_f32_16x16x32_bf16((a), (b), (c), 0, 0, 0)
#define WVM5() asm volatile("s_waitcnt vmcnt(5)" ::: "memory")
#define WVM0() asm volatile("s_waitcnt vmcnt(0)" ::: "memory")

// ---------------------------------------------------------------------------
__global__ __launch_bounds__(256) void base_kernel(
    const float* __restrict__ enc, const float* __restrict__ W_in,
    const float* __restrict__ b_in, float* __restrict__ base)
{
  int b = blockIdx.x, j = threadIdx.x;
  __shared__ float se[256];
  se[j] = enc[b * 256 + j];
  __syncthreads();
  float acc = b_in[j] + W_in[j];
  for (int i = 1; i < 256; ++i) acc += se[i] * W_in[i * 256 + j];
  base[b * 256 + j] = acc;
}

// h row-major bf16 + fragment-order hbP
__global__ __launch_bounds__(256) void embed_kernel(
    const float* __restrict__ base, const int* __restrict__ batch_idx,
    const float* __restrict__ pos, const float* __restrict__ W_in,
    ushort_t* __restrict__ h_bf, ushort_t* __restrict__ hbP)
{
  int n = blockIdx.x, j = threadIdx.x;
  int b = batch_idx[n];
  float px = pos[n * 3 + 0], py = pos[n * 3 + 1], pz = pos[n * 3 + 2];
  float v = base[b * 256 + j]
      + px * W_in[256 * 256 + j] + py * W_in[257 * 256 + j] + pz * W_in[258 * 256 + j];
  ushort_t u = f2b(v);
  h_bf[(size_t)n * 256 + j] = u;
  int rt = n >> 4, ct = j >> 4;
  int lane = ((n & 15) >> 2) * 16 + (j & 15);
  hbP[(((size_t)rt * 16 + ct) * 64 + lane) * 4 + (n & 3)] = u;
}

// ---------------------------------------------------------------------------
// W3P (qkv): block (ct*8+ks), 1KB fragment blocks
__global__ __launch_bounds__(256) void prep_qkv(
    const float* __restrict__ Wq, const float* __restrict__ Wk,
    const float* __restrict__ Wv, const float* __restrict__ We,
    ushort_t* __restrict__ out)
{
  int idx = blockIdx.x * 256 + threadIdx.x;  // < 4*640*256
  int l = idx / (640 * 256);
  int rem = idx - l * (640 * 256);
  int c = rem >> 8, k = rem & 255;
  float v = 0.f;
  if (c < 128) v = Wq[((size_t)l * 256 + k) * 128 + c];
  else if (c < 328) {
    int p = c - 128, hq = p / 50, r = p - hq * 50;
    const float* wq = &Wq[((size_t)l * 256 + k) * 128 + hq * 32];
    const float* we = &We[((size_t)l * 50 + r) * 128 + hq * 32];
#pragma unroll
    for (int d = 0; d < 32; ++d) v += wq[d] * we[d];
  } else if (c < 456) v = Wk[((size_t)l * 256 + k) * 128 + (c - 328)];
  else if (c < 584) v = Wv[((size_t)l * 256 + k) * 128 + (c - 456)];
  size_t pos = (size_t)l * 163840
      + (((c >> 4) * 8 + (k >> 5)) * 64 + ((k >> 3) & 3) * 16 + (c & 15)) * 8 + (k & 7);
  out[pos] = f2b(v);
}

// BcP: block (ks*16+ct), K=352
__global__ __launch_bounds__(256) void prep_bcat(
    const float* __restrict__ We, const float* __restrict__ Wo, ushort_t* __restrict__ out)
{
  int idx = blockIdx.x * 256 + threadIdx.x;  // < 4*256*352
  if (idx >= 4 * 256 * 352) return;
  int l = idx / (256 * 352);
  int rem = idx - l * (256 * 352);
  int c = rem / 352, k = rem - c * 352;
  float v = 0.f;
  if (k < 128) v = Wo[((size_t)l * 128 + k) * 256 + c];
  else if (k < 328) {
    int p = k - 128, hq = p / 50, r = p - hq * 50;
    const float* we = &We[((size_t)l * 50 + r) * 128 + hq * 32];
    const float* wo = &Wo[((size_t)l * 128 + hq * 32) * 256 + c];
#pragma unroll
    for (int d = 0; d < 32; ++d) v += we[d] * wo[(size_t)d * 256];
  }
  size_t pos = (size_t)l * 90112
      + (((k >> 5) * 16 + (c >> 4)) * 64 + ((k >> 3) & 3) * 16 + (c & 15)) * 8 + (k & 7);
  out[pos] = f2b(v);
}

// WfP: block (ks*16+ct)
__global__ __launch_bounds__(256) void prep_wfc(
    const float* __restrict__ Wfc, ushort_t* __restrict__ out)
{
  int idx = blockIdx.x * 256 + threadIdx.x;  // < 4*256*256
  int l = idx >> 16, rem = idx & 65535;
  int c = rem >> 8, k = rem & 255;
  float v = Wfc[((size_t)l * 256 + k) * 256 + c];
  size_t pos = (size_t)l * 65536
      + (((k >> 5) * 16 + (c >> 4)) * 64 + ((k >> 3) & 3) * 16 + (c & 15)) * 8 + (k & 7);
  out[pos] = f2b(v);
}

// WoP: block (ct*8+ks), cols padded to 128
__global__ __launch_bounds__(256) void prep_wout(
    const float* __restrict__ W_out, ushort_t* __restrict__ out)
{
  int idx = blockIdx.x * 256 + threadIdx.x;  // < 128*256
  int c = idx >> 8, k = idx & 255;
  float v = (c < 103) ? W_out[(size_t)k * 103 + c] : 0.f;
  size_t pos = (((c >> 4) * 8 + (k >> 5)) * 64 + ((k >> 3) & 3) * 16 + (c & 15)) * 8 + (k & 7);
  out[pos] = f2b(v);
}

// ---------------------------------------------------------------------------
// Fused layer v9b: per-wave async B-stream, FULLY UNROLLED stream loops
// (rule #20: all acc indices compile-time -> registers, no scratch).
// 512 blocks x 256 thr (4 waves), 32 rows/block; wave owns a column quarter.
// Per-wave 8-slot LDS ring, counted per-wave vmcnt(5), zero GEMM barriers.
// MODE 0: full layer -> qkv. MODE 1: full layer -> out. MODE 2: qkv only.
template<int MODE>
__global__ __launch_bounds__(256) void fused_layer(
    const ushort_t* __restrict__ Amsg,  // [N][352] (MODE!=2)
    const ushort_t* __restrict__ BcP,   // packed, block (ks*16+ct), ks<11
    const float* __restrict__ bo,
    ushort_t* __restrict__ hbP,         // fragment-order residual stream
    const float* __restrict__ lg, const float* __restrict__ lb,
    const ushort_t* __restrict__ WfP,   // packed, block (ks*16+ct), ks<8
    const float* __restrict__ bfc,
    const ushort_t* __restrict__ W3P,   // packed, block (ct*8+ks); 40 or 8 ct
    const float* __restrict__ b3,
    const ushort_t* __restrict__ h_bf,  // row-major h (MODE 2)
    ushort_t* __restrict__ qext_b, ushort_t* __restrict__ kvb,
    float* __restrict__ outF)
{
  __shared__ __align__(16) ushort_t sA[32 * 384];   // A (G1); then gelu (ld 256)
  __shared__ __align__(16) ushort_t sH[32 * 256];   // hln (ld 256, swizzled)
  __shared__ __align__(16) ushort_t ring[4 * 8 * 512];  // 4 waves x 8 x 1KB
  __shared__ float pS[4][32], pSS[4][32];

  const int tid = threadIdx.x;
  const int lane = tid & 63, wv = tid >> 6;
  const int l15 = lane & 15, l4 = lane >> 4;
  const int r7 = l15 & 7;
  const int r0 = blockIdx.x * 32;
  const int rtg = blockIdx.x * 2;
  ushort_t* ring_w = ring + wv * (8 * 512);
  const int loff = lane * 8;

  if constexpr (MODE != 2) {
    // ---- stage Amsg tile -> sA [32][384], XOR-swizzled, zero K-pad
    for (int i = tid; i < 32 * 48; i += 256) {
      int r = i / 48, c8 = i - r * 48;
      uint4 v = (uint4){0, 0, 0, 0};
      if (c8 < 44) v = *(const uint4*)(Amsg + (size_t)(r0 + r) * 352 + c8 * 8);
      *(uint4*)(&sA[r * 384 + ((c8 ^ (r & 7)) << 3)]) = v;
    }
    __syncthreads();

    const int cb = wv * 4;

    // ================= GEMM1: K=352, 44 stream-iters (unrolled) ==========
    f32x4 acc[2][4];
#pragma unroll
    for (int m = 0; m < 2; ++m)
#pragma unroll
      for (int j = 0; j < 4; ++j) acc[m][j] = (f32x4){0.f, 0.f, 0.f, 0.f};
#pragma unroll
    for (int p = 0; p < 6; ++p) {
      int blk = (p >> 2) * 16 + cb + (p & 3);
      gload16(BcP + (size_t)blk * 512 + loff, ring_w + (p & 7) * 512);
    }
    {
      bfrag a0, a1;
#pragma unroll
      for (int i = 0; i < 44; ++i) {
        WVM5();
        const int ks = i >> 2, j = i & 3;
        bfrag b = *(const bfrag*)(ring_w + (i & 7) * 512 + loff);
        if (j == 0) {
          const int ch = ks * 4 + l4;
          a0 = *(const bfrag*)(sA + l15 * 384 + ((ch ^ r7) << 3));
          a1 = *(const bfrag*)(sA + (16 + l15) * 384 + ((ch ^ r7) << 3));
        }
        __builtin_amdgcn_s_setprio(1);
        acc[0][j] = MFMA16(a0, b, acc[0][j]);
        acc[1][j] = MFMA16(a1, b, acc[1][j]);
        __builtin_amdgcn_s_setprio(0);
        int pn = i + 6; if (pn > 43) pn = 43;
        int blkn = (pn >> 2) * 16 + cb + (pn & 3);
        gload16(BcP + (size_t)blkn * 512 + loff, ring_w + ((i + 6) & 7) * 512);
      }
      WVM0();
    }

    // ---- epilogue 1: + bo + resid(hbP), partial LN stats
#pragma unroll
    for (int m = 0; m < 2; ++m)
#pragma unroll
      for (int i = 0; i < 4; ++i) {
        const int rl = m * 16 + l4 * 4 + i;
        float s = 0.f, q = 0.f;
#pragma unroll
        for (int j = 0; j < 4; ++j) {
          const int c = (cb + j) * 16 + l15;
          float hv = b2f(hbP[(((size_t)(rtg + m) * 16 + cb + j) * 64 + lane) * 4 + i]);
          float x = acc[m][j][i] + bo[c] + hv;
          acc[m][j][i] = x;
          s += x; q += x * x;
        }
#pragma unroll
        for (int off = 1; off < 16; off <<= 1) {
          s += __shfl_xor(s, off, 64);
          q += __shfl_xor(q, off, 64);
        }
        if (l15 == 0) { pS[wv][rl] = s; pSS[wv][rl] = q; }
      }
    __syncthreads();
    // ---- LN -> sH (ld 256, swizzled)
#pragma unroll
    for (int m = 0; m < 2; ++m)
#pragma unroll
      for (int i = 0; i < 4; ++i) {
        const int rl = m * 16 + l4 * 4 + i;
        float S = pS[0][rl] + pS[1][rl] + pS[2][rl] + pS[3][rl];
        float Q = pSS[0][rl] + pSS[1][rl] + pSS[2][rl] + pSS[3][rl];
        float mu = S * (1.f / 256.f);
        float var = Q * (1.f / 256.f) - mu * mu;
        float inv = 1.0f / sqrtf(var + 1e-5f);
#pragma unroll
        for (int j = 0; j < 4; ++j) {
          const int c = (cb + j) * 16 + l15;
          sH[rl * 256 + ((((c >> 3) ^ (rl & 7)) << 3) | (c & 7))] =
              f2b(lg[c] * (acc[m][j][i] - mu) * inv + lb[c]);
        }
      }
    __syncthreads();

    // ================= GEMM2: K=256, 32 stream-iters (unrolled) ==========
#pragma unroll
    for (int m = 0; m < 2; ++m)
#pragma unroll
      for (int j = 0; j < 4; ++j) acc[m][j] = (f32x4){0.f, 0.f, 0.f, 0.f};
#pragma unroll
    for (int p = 0; p < 6; ++p) {
      int blk = (p >> 2) * 16 + cb + (p & 3);
      gload16(WfP + (size_t)blk * 512 + loff, ring_w + (p & 7) * 512);
    }
    {
      bfrag a0, a1;
#pragma unroll
      for (int i = 0; i < 32; ++i) {
        WVM5();
        const int ks = i >> 2, j = i & 3;
        bfrag b = *(const bfrag*)(ring_w + (i & 7) * 512 + loff);
        if (j == 0) {
          const int ch = ks * 4 + l4;
          a0 = *(const bfrag*)(sH + l15 * 256 + ((ch ^ r7) << 3));
          a1 = *(const bfrag*)(sH + (16 + l15) * 256 + ((ch ^ r7) << 3));
        }
        __builtin_amdgcn_s_setprio(1);
        acc[0][j] = MFMA16(a0, b, acc[0][j]);
        acc[1][j] = MFMA16(a1, b, acc[1][j]);
        __builtin_amdgcn_s_setprio(0);
        int pn = i + 6; if (pn > 31) pn = 31;
        int blkn = (pn >> 2) * 16 + cb + (pn & 3);
        gload16(WfP + (size_t)blkn * 512 + loff, ring_w + ((i + 6) & 7) * 512);
      }
      WVM0();
    }

    // ---- epilogue 2: gelu -> hbP (frag-order) + sA (ld 256, swizzled)
#pragma unroll
    for (int m = 0; m < 2; ++m)
#pragma unroll
      for (int j = 0; j < 4; ++j) {
        const int c = (cb + j) * 16 + l15;
        const float bfcc = bfc[c];
        ushort_t uo[4];
#pragma unroll
        for (int i = 0; i < 4; ++i) {
          const int rl = m * 16 + l4 * 4 + i;
          float x = acc[m][j][i] + bfcc;
          float t = tanhf(0.7978845608028654f * (x + 0.044715f * x * x * x));
          float gl = 0.5f * x * (1.f + t);
          uo[i] = f2b(gl);
          sA[rl * 256 + ((((c >> 3) ^ (rl & 7)) << 3) | (c & 7))] = uo[i];
        }
        *(uint2*)(hbP + (((size_t)(rtg + m) * 16 + cb + j) * 64 + lane) * 4) =
            *(const uint2*)uo;
      }
    __syncthreads();
  } else {
    // MODE 2: stage h_bf tile -> sA (ld 256, swizzled)
    for (int i = tid; i < 32 * 32; i += 256) {
      int r = i >> 5, c8 = i & 31;
      *(uint4*)(&sA[r * 256 + ((c8 ^ (r & 7)) << 3)]) =
          *(const uint4*)(h_bf + (size_t)(r0 + r) * 256 + c8 * 8);
    }
    __syncthreads();
  }

  // ================= GEMM3: K=256, ct chunks, per-wave stream (unrolled) ==
  {
    constexpr int CTC = (MODE == 1) ? 2 : 5;
    constexpr int NCH = (MODE == 1) ? 1 : 2;
    constexpr int NPC = 8 * CTC;
    constexpr int NI3 = NCH * NPC;
    const int cg = wv * (CTC * NCH);
#pragma unroll
    for (int p = 0; p < 6; ++p) {
      int ks = p / CTC, j = p - ks * CTC;
      int blk = (cg + j) * 8 + ks;
      gload16(W3P + (size_t)blk * 512 + loff, ring_w + (p & 7) * 512);
    }
    f32x4 a3[2][CTC];
    bfrag a0, a1;
#pragma unroll
    for (int i = 0; i < NI3; ++i) {
      const int chunk = i / NPC;
      const int rr = i - chunk * NPC;
      const int ks = rr / CTC, j = rr - ks * CTC;
      if (rr == 0) {
#pragma unroll
        for (int m = 0; m < 2; ++m)
#pragma unroll
          for (int t = 0; t < CTC; ++t) a3[m][t] = (f32x4){0.f, 0.f, 0.f, 0.f};
      }
      WVM5();
      bfrag b = *(const bfrag*)(ring_w + (i & 7) * 512 + loff);
      if (j == 0) {
        const int ch = ks * 4 + l4;
        a0 = *(const bfrag*)(sA + l15 * 256 + ((ch ^ r7) << 3));
        a1 = *(const bfrag*)(sA + (16 + l15) * 256 + ((ch ^ r7) << 3));
      }
      __builtin_amdgcn_s_setprio(1);
      a3[0][j] = MFMA16(a0, b, a3[0][j]);
      a3[1][j] = MFMA16(a1, b, a3[1][j]);
      __builtin_amdgcn_s_setprio(0);
      if (rr == NPC - 1) {
        const int ctb = cg + chunk * CTC;
#pragma unroll
        for (int t = 0; t < CTC; ++t) {
          const int c = (ctb + t) * 16 + l15;
#pragma unroll
          for (int m = 0; m < 2; ++m)
#pragma unroll
            for (int i2 = 0; i2 < 4; ++i2) {
              const size_t r = (size_t)(r0 + m * 16 + l4 * 4 + i2);
              float v = a3[m][t][i2];
              if constexpr (MODE == 1) {
                if (c < 103) outF[r * 103 + c] = v + b3[c];
              } else {
                if (c < 328) qext_b[r * 352 + c] = f2b(v);
                else if (c < 584) kvb[r * 256 + (c - 328)] = f2b(v);
              }
            }
        }
      }
      int pn = i + 6; if (pn > NI3 - 1) pn = NI3 - 1;
      const int pch = pn / NPC;
      const int prr = pn - pch * NPC;
      const int pks = prr / CTC, pj = prr - pks * CTC;
      int blkn = (cg + pch * CTC + pj) * 8 + pks;
      gload16(W3P + (size_t)blkn * 512 + loff, ring_w + ((i + 6) & 7) * 512);
    }
    WVM0();
  }
}

// ---------------------------------------------------------------------------
// Attention: K/V straight from L2, all LDS per-wave, no block barriers.
__global__ __launch_bounds__(256) void attn_kernel(
    const ushort_t* __restrict__ qext, const ushort_t* __restrict__ kvb,
    const float* __restrict__ pos, const int* __restrict__ nbrs,
    const float* __restrict__ mask, ushort_t* __restrict__ Amsg)
{
  __shared__ __align__(16) ushort_t sQ[4][128];
  __shared__ __align__(16) float    sQE[4][4][52];
  __shared__ __align__(16) ushort_t sRbf[4][16][52];
  __shared__ float sA[4][64];
  __shared__ float sD[4][16];
  __shared__ float sMk[4][16];
  __shared__ int   sNb[4][16];

  const int tid = threadIdx.x;
  const int bid = blockIdx.x;
  const int lane = tid & 63, w = tid >> 6;
  const int g = (bid & 7) + 8 * ((bid >> 3) & 15);
  const int q4 = bid >> 7;
  const int kk = lane >> 2, hh = lane & 3;

  for (int it = 0; it < 4; ++it) {
    const int n = g * 128 + q4 * 16 + w * 4 + it;
    if (lane < 16) {
      int nb = nbrs[n * 16 + lane];
      sNb[w][lane] = nb;
      sMk[w][lane] = mask[n * 16 + lane];
      float dx = pos[nb * 3 + 0] - pos[n * 3 + 0];
      float dy = pos[nb * 3 + 1] - pos[n * 3 + 1];
      float dz = pos[nb * 3 + 2] - pos[n * 3 + 2];
      sD[w][lane] = sqrtf(dx * dx + dy * dy + dz * dz + 1e-12f);
      sRbf[w][lane][50] = 0; sRbf[w][lane][51] = 0;
      *(uint4*)(&sQ[w][lane * 8]) = *(const uint4*)(qext + (size_t)n * 352 + lane * 8);
    }
    if (lane < 50) {
      uint2 u = *(const uint2*)(qext + (size_t)n * 352 + 128 + lane * 4);
      int p = lane * 4;
#pragma unroll
      for (int e = 0; e < 4; ++e) {
        ushort_t bb = ((const ushort_t*)&u)[e];
        int pp = p + e, h2 = pp / 50, r = pp - h2 * 50;
        sQE[w][h2][r] = b2f(bb);
      }
    }
    if (lane < 8) sQE[w][lane >> 1][50 + (lane & 1)] = 0.f;
    {
      int kk2 = lane & 15;
      float dk = sD[w][kk2];
      int r0 = lane >> 4;
#pragma unroll
      for (int j = 0; j < 13; ++j) {
        int r = r0 + j * 4;
        if (r < 50) {
          float t = (dk - (2.f / 49.f) * (float)r) * 24.5f;
          sRbf[w][kk2][r] = f2b(__expf(-0.5f * t * t));
        }
      }
    }
    const int nb = sNb[w][kk];
    const ushort_t* krow = kvb + (size_t)nb * 256 + hh * 32;
    float qk = 0.f;
#pragma unroll
    for (int c8 = 0; c8 < 4; ++c8) {
      uint4 kv4 = *(const uint4*)(krow + c8 * 8);
      const uint_t* q4p = (const uint_t*)(&sQ[w][hh * 32 + c8 * 8]);
      uint_t qa = q4p[0], qb = q4p[1], qc = q4p[2], qd = q4p[3];
      qk += blo(qa) * blo(kv4.x) + bhi(qa) * bhi(kv4.x)
          + blo(qb) * blo(kv4.y) + bhi(qb) * bhi(kv4.y)
          + blo(qc) * blo(kv4.z) + bhi(qc) * bhi(kv4.z)
          + blo(qd) * blo(kv4.w) + bhi(qd) * bhi(kv4.w);
    }
    float qe = 0.f;
#pragma unroll
    for (int c = 0; c < 13; ++c) {
      float4 qv = *(const float4*)(&sQE[w][hh][c * 4]);
      uint2 rv = *(const uint2*)(&sRbf[w][kk][c * 4]);
      qe += qv.x * blo(rv.x) + qv.y * bhi(rv.x)
          + qv.z * blo(rv.y) + qv.w * bhi(rv.y);
    }
    float lg = 0.17677669529663687f * (qk + qe);
    lg = (sMk[w][kk] > 0.f) ? lg : -1e9f;

    float mx = lg;
#pragma unroll
    for (int off = 4; off < 64; off <<= 1) mx = fmaxf(mx, __shfl_xor(mx, off, 64));
    float ex = __expf(lg - mx);
    float sm = ex;
#pragma unroll
    for (int off = 4; off < 64; off <<= 1) sm += __shfl_xor(sm, off, 64);
    sA[w][kk * 4 + hh] = ex / sm * sMk[w][kk];

    if (lane < 50) {
      float r0 = 0.f, r1 = 0.f, r2 = 0.f, r3 = 0.f;
#pragma unroll
      for (int k2 = 0; k2 < 16; ++k2) {
        float rb = b2f(sRbf[w][k2][lane]);
        r0 += sA[w][k2 * 4 + 0] * rb;
        r1 += sA[w][k2 * 4 + 1] * rb;
        r2 += sA[w][k2 * 4 + 2] * rb;
        r3 += sA[w][k2 * 4 + 3] * rb;
      }
      Amsg[(size_t)n * 352 + 128 + 0 * 50 + lane] = f2b(r0);
      Amsg[(size_t)n * 352 + 128 + 1 * 50 + lane] = f2b(r1);
      Amsg[(size_t)n * 352 + 128 + 2 * 50 + lane] = f2b(r2);
      Amsg[(size_t)n * 352 + 128 + 3 * 50 + lane] = f2b(r3);
    }
    {
      const int h2 = lane >> 4;
      float m0v = 0.f, m1v = 0.f;
#pragma unroll
      for (int k2 = 0; k2 < 16; ++k2) {
        int nb2 = sNb[w][k2];
        uint_t vv = *(const uint_t*)(kvb + (size_t)nb2 * 256 + 128 + lane * 2);
        float a = sA[w][k2 * 4 + h2];
        m0v += a * blo(vv);
        m1v += a * bhi(vv);
      }
      uint_t o = (uint_t)f2b(m0v) | ((uint_t)f2b(m1v) << 16);
      *(uint_t*)(&Amsg[(size_t)n * 352 + lane * 2]) = o;
    }
    if (lane < 24) Amsg[(size_t)n * 352 + 328 + lane] = 0;
  }
}

// ---------------------------------------------------------------------------
extern "C" void kernel_launch(void* const* d_in, const int* in_sizes, int n_in,
                              void* d_out, int out_size, void* d_ws, size_t ws_size,
                              hipStream_t stream) {
  const float* enc    = (const float*)d_in[0];
  const float* pos    = (const float*)d_in[1];
  const int*   bidx   = (const int*)  d_in[2];
  const int*   nbrs   = (const int*)  d_in[3];
  const float* mask   = (const float*)d_in[4];
  const float* W_in   = (const float*)d_in[5];
  const float* b_in   = (const float*)d_in[6];
  const float* Wq     = (const float*)d_in[7];
  const float* Wk     = (const float*)d_in[8];
  const float* Wv     = (const float*)d_in[9];
  const float* We     = (const float*)d_in[10];
  const float* Wo     = (const float*)d_in[11];
  const float* bo     = (const float*)d_in[12];
  const float* Wfc    = (const float*)d_in[13];
  const float* bfc    = (const float*)d_in[14];
  const float* ln_g   = (const float*)d_in[15];
  const float* ln_b   = (const float*)d_in[16];
  const float* W_out  = (const float*)d_in[17];
  const float* b_out  = (const float*)d_in[18];
  float* out = (float*)d_out;

  const int N = N_PTS;
  ushort_t* ws = (ushort_t*)d_ws;
  ushort_t* hbP    = ws;                                  // N*256 frag-order
  ushort_t* h_bf   = hbP + (size_t)N * 256;               // N*256 row-major
  ushort_t* qext_b = h_bf + (size_t)N * 256;              // N*352
  ushort_t* kvb    = qext_b + (size_t)N * 352;            // N*256
  ushort_t* Amsg   = kvb + (size_t)N * 256;               // N*352
  float*    base   = (float*)(Amsg + (size_t)N * 352);    // 128*256 fp32
  ushort_t* W3P    = (ushort_t*)(base + 128 * 256);       // 4*163840
  ushort_t* BcP    = W3P + 4 * 163840;                    // 4*90112
  ushort_t* WfP    = BcP + 4 * 90112;                     // 4*65536
  ushort_t* WoP    = WfP + 4 * 65536;                     // 32768

  base_kernel<<<128, 256, 0, stream>>>(enc, W_in, b_in, base);
  embed_kernel<<<N, 256, 0, stream>>>(base, bidx, pos, W_in, h_bf, hbP);
  prep_qkv<<<(4 * 640 * 256) / 256, 256, 0, stream>>>(Wq, Wk, Wv, We, W3P);
  prep_bcat<<<(4 * 256 * 352 + 255) / 256, 256, 0, stream>>>(We, Wo, BcP);
  prep_wfc<<<(4 * 256 * 256) / 256, 256, 0, stream>>>(Wfc, WfP);
  prep_wout<<<(128 * 256) / 256, 256, 0, stream>>>(W_out, WoP);

  // layer-0 qkv from embedded features
  fused_layer<2><<<N / 32, 256, 0, stream>>>(
      nullptr, nullptr, nullptr, nullptr, nullptr, nullptr, nullptr, nullptr,
      W3P, nullptr, h_bf, qext_b, kvb, nullptr);

  for (int l = 0; l < NLAYER; ++l) {
    const ushort_t* BcP_l = BcP + (size_t)l * 90112;
    const ushort_t* WfP_l = WfP + (size_t)l * 65536;
    const float* bo_l  = bo  + (size_t)l * 256;
    const float* bfc_l = bfc + (size_t)l * 256;
    const float* lg_l  = ln_g + (size_t)l * 256;
    const float* lb_l  = ln_b + (size_t)l * 256;

    attn_kernel<<<1024, 256, 0, stream>>>(qext_b, kvb, pos, nbrs, mask, Amsg);

    if (l < NLAYER - 1) {
      const ushort_t* W3P_next = W3P + (size_t)(l + 1) * 163840;
      fused_layer<0><<<N / 32, 256, 0, stream>>>(
          Amsg, BcP_l, bo_l, hbP, lg_l, lb_l, WfP_l, bfc_l,
          W3P_next, nullptr, nullptr, qext_b, kvb, nullptr);
    } else {
      fused_layer<1><<<N / 32, 256, 0, stream>>>(
          Amsg, BcP_l, bo_l, hbP, lg_l, lb_l, WfP_l, bfc_l,
          WoP, b_out, nullptr, nullptr, nullptr, out);
    }
  }
}

// Round 17
// 324.948 us; speedup vs baseline: 2.0616x; 2.0496x over previous
//
#include <hip/hip_runtime.h>
#include <hip/hip_bf16.h>
#include <math.h>

#define N_PTS 16384
#define NLAYER 4

typedef __attribute__((ext_vector_type(8))) short bfrag;
typedef __attribute__((ext_vector_type(4))) float f32x4;
typedef unsigned short ushort_t;
typedef unsigned int uint_t;

__device__ __forceinline__ ushort_t f2b(float f) {
  __hip_bfloat16 h = __float2bfloat16(f);
  return *reinterpret_cast<const ushort_t*>(&h);
}
__device__ __forceinline__ float b2f(ushort_t u) {
  union { uint_t i; float f; } c; c.i = ((uint_t)u) << 16; return c.f;
}
__device__ __forceinline__ float blo(uint_t u) {
  union { uint_t i; float f; } c; c.i = u << 16; return c.f;
}
__device__ __forceinline__ float bhi(uint_t u) {
  union { uint_t i; float f; } c; c.i = u & 0xffff0000u; return c.f;
}

// async global->LDS, 16B/lane; LDS dest must be wave-uniform; HW adds lane*16.
__device__ __forceinline__ void gload16(const ushort_t* g, ushort_t* l) {
  __builtin_amdgcn_global_load_lds(
      (const __attribute__((address_space(1))) unsigned int*)g,
      (__attribute__((address_space(3))) unsigned int*)l, 16, 0, 0);
}

#define MFMA16(a, b, c) __builtin_amdgcn_mfma_f32_16x16x32_bf16((a), (b), (c), 0, 0, 0)

// ---------------------------------------------------------------------------
__global__ __launch_bounds__(256) void base_kernel(
    const float* __restrict__ enc, const float* __restrict__ W_in,
    const float* __restrict__ b_in, float* __restrict__ base)
{
  int b = blockIdx.x, j = threadIdx.x;
  __shared__ float se[256];
  se[j] = enc[b * 256 + j];
  __syncthreads();
  float acc = b_in[j] + W_in[j];
  for (int i = 1; i < 256; ++i) acc += se[i] * W_in[i * 256 + j];
  base[b * 256 + j] = acc;
}

__global__ __launch_bounds__(256) void embed_kernel(
    const float* __restrict__ base, const int* __restrict__ batch_idx,
    const float* __restrict__ pos, const float* __restrict__ W_in,
    ushort_t* __restrict__ h_bf)
{
  int n = blockIdx.x, j = threadIdx.x;
  int b = batch_idx[n];
  float px = pos[n * 3 + 0], py = pos[n * 3 + 1], pz = pos[n * 3 + 2];
  float v = base[b * 256 + j]
      + px * W_in[256 * 256 + j] + py * W_in[257 * 256 + j] + pz * W_in[258 * 256 + j];
  h_bf[(size_t)n * 256 + j] = f2b(v);
}

// ---------------------------------------------------------------------------
__global__ __launch_bounds__(256) void prep_qkv(
    const float* __restrict__ Wq, const float* __restrict__ Wk,
    const float* __restrict__ Wv, const float* __restrict__ We,
    ushort_t* __restrict__ out)
{
  int idx = blockIdx.x * 256 + threadIdx.x;  // < 4*640*256
  int l = idx / (640 * 256);
  int rem = idx - l * (640 * 256);
  int j = rem >> 8, k = rem & 255;
  float v = 0.f;
  if (j < 128) v = Wq[((size_t)l * 256 + k) * 128 + j];
  else if (j < 328) {
    int p = j - 128, hq = p / 50, r = p - hq * 50;
    const float* wq = &Wq[((size_t)l * 256 + k) * 128 + hq * 32];
    const float* we = &We[((size_t)l * 50 + r) * 128 + hq * 32];
#pragma unroll
    for (int d = 0; d < 32; ++d) v += wq[d] * we[d];
  } else if (j < 456) v = Wk[((size_t)l * 256 + k) * 128 + (j - 328)];
  else if (j < 584) v = Wv[((size_t)l * 256 + k) * 128 + (j - 456)];
  out[idx] = f2b(v);
}

__global__ __launch_bounds__(256) void prep_bcat(
    const float* __restrict__ We, const float* __restrict__ Wo, ushort_t* __restrict__ out)
{
  int idx = blockIdx.x * 256 + threadIdx.x;  // < 4*256*384
  int l = idx / (256 * 384);
  int rem = idx - l * (256 * 384);
  int j = rem / 384, k2 = rem - j * 384;
  float v = 0.f;
  if (k2 < 128) v = Wo[((size_t)l * 128 + k2) * 256 + j];
  else if (k2 < 328) {
    int p = k2 - 128, hq = p / 50, r = p - hq * 50;
    const float* we = &We[((size_t)l * 50 + r) * 128 + hq * 32];
    const float* wo = &Wo[((size_t)l * 128 + hq * 32) * 256 + j];
#pragma unroll
    for (int d = 0; d < 32; ++d) v += we[d] * wo[(size_t)d * 256];
  }
  out[idx] = f2b(v);
}

__global__ __launch_bounds__(256) void prep_wfc(
    const float* __restrict__ Wfc, ushort_t* __restrict__ out)
{
  int idx = blockIdx.x * 256 + threadIdx.x;  // < 4*256*256
  int l = idx >> 16, rem = idx & 65535;
  int j = rem >> 8, k = rem & 255;
  out[idx] = f2b(Wfc[((size_t)l * 256 + k) * 256 + j]);
}

__global__ __launch_bounds__(256) void prep_wout(
    const float* __restrict__ W_out, ushort_t* __restrict__ out)
{
  int idx = blockIdx.x * 256 + threadIdx.x;  // < 128*256
  int j = idx >> 8, k = idx & 255;
  out[idx] = (j < 103) ? f2b(W_out[(size_t)k * 103 + j]) : (ushort_t)0;
}

// ---------------------------------------------------------------------------
// Fused layer tail v6 (champion): B staged via global_load_lds double-buffer.
// 512 blocks x 512 thr, 32 rows/block, XCD-colocated grid mapping.
// B-tile layouts: G1/G2 c-major [c][4kc]; G3 K-major [8kc][128c].
// MODE 0: full layer -> qkv. MODE 1: full layer -> out. MODE 2: qkv only.
template<int MODE>
__global__ __launch_bounds__(512, 4) void fused_layer(
    const ushort_t* __restrict__ A0,    // MODE2: h_bf (ld 256); else Amsg (ld 352)
    const ushort_t* __restrict__ BcT,   // [256][384]
    const float* __restrict__ bo,
    ushort_t* __restrict__ hb,          // bf16 residual in / gelu out
    const float* __restrict__ lg, const float* __restrict__ lb,
    const ushort_t* __restrict__ WfT,   // [256][256]
    const float* __restrict__ bfc,
    const ushort_t* __restrict__ W3T,   // [640][256] (qkv) or [128][256] (out)
    const float* __restrict__ b3,
    ushort_t* __restrict__ qext_b, ushort_t* __restrict__ kvb,
    float* __restrict__ outF)
{
  __shared__ __align__(16) ushort_t sA[32 * 384];   // GEMM1 A; later sHg (ld 256)
  __shared__ __align__(16) ushort_t sH[32 * 256];   // hln
  __shared__ __align__(16) ushort_t sB[2][8192];    // B double-buffer, 16 KB each
  __shared__ float pS[8][32], pSS[8][32];

  const int tid = threadIdx.x;
  const int bid = blockIdx.x;
  const int lane = tid & 63, w = tid >> 6;
  const int l15 = lane & 15, l4 = lane >> 4;
  const int m0 = ((bid & 7) + 8 * ((bid >> 3) & 15)) * 128 + (bid >> 7) * 32;
  const int r7 = l15 & 7;
  const int q0 = w * 64 + lane;        // staging chunk id (j=0); j=1 adds 512

  f32x4 acc[2][2];

  if constexpr (MODE != 2) {
    // ---- issue GEMM1 B-stage (k0=0) into sB[0]: [c][kc] c-major
    gload16(BcT + (size_t)(q0 >> 2) * 384 + ((q0 & 3) << 3),
            (ushort_t*)&sB[0][(w * 64) << 3]);
    gload16(BcT + (size_t)((q0 + 512) >> 2) * 384 + (((q0 + 512) & 3) << 3),
            (ushort_t*)&sB[0][(512 + w * 64) << 3]);

    // ---- stage Amsg tile -> sA [32][384], 16B-chunk XOR swizzle, zero pad
    for (int i = tid; i < 32 * 48; i += 512) {
      int r = i / 48, c8 = i - r * 48;
      uint4 v = (uint4){0, 0, 0, 0};
      if (c8 < 44) v = *(const uint4*)(A0 + (size_t)(m0 + r) * 352 + c8 * 8);
      *(uint4*)(&sA[r * 384 + ((c8 ^ (r & 7)) << 3)]) = v;
    }
    __syncthreads();

    const int c0 = w * 32 + l15, c1 = c0 + 16;

    // ---- GEMM1: acc = Amsg @ BcT^T  (K=352, 11 double-buffered phases)
#pragma unroll
    for (int m = 0; m < 2; ++m) {
      acc[m][0] = (f32x4){0.f, 0.f, 0.f, 0.f};
      acc[m][1] = (f32x4){0.f, 0.f, 0.f, 0.f};
    }
    for (int ks = 0; ks < 11; ++ks) {
      if (ks < 10) {
        const int k0n = (ks + 1) * 32;
        ushort_t* db = (ushort_t*)sB[(ks + 1) & 1];
        gload16(BcT + (size_t)(q0 >> 2) * 384 + k0n + ((q0 & 3) << 3),
                db + ((w * 64) << 3));
        gload16(BcT + (size_t)((q0 + 512) >> 2) * 384 + k0n + (((q0 + 512) & 3) << 3),
                db + ((512 + w * 64) << 3));
      }
      const ushort_t* bbuf = sB[ks & 1];
      const int ch = ((ks * 32) >> 3) + l4;
      bfrag a0 = *(const bfrag*)(sA + l15 * 384 + ((ch ^ r7) << 3));
      bfrag a1 = *(const bfrag*)(sA + (16 + l15) * 384 + ((ch ^ r7) << 3));
      bfrag b0 = *(const bfrag*)(bbuf + ((c0 * 4 + l4) << 3));
      bfrag b1 = *(const bfrag*)(bbuf + ((c1 * 4 + l4) << 3));
      __builtin_amdgcn_s_setprio(1);
      acc[0][0] = MFMA16(a0, b0, acc[0][0]);
      acc[0][1] = MFMA16(a0, b1, acc[0][1]);
      acc[1][0] = MFMA16(a1, b0, acc[1][0]);
      acc[1][1] = MFMA16(a1, b1, acc[1][1]);
      __builtin_amdgcn_s_setprio(0);
      __syncthreads();
    }

    // ---- issue GEMM2 B-stage (k0=0) into sB[0] (flies under epilogue 1)
    gload16(WfT + (size_t)(q0 >> 2) * 256 + ((q0 & 3) << 3),
            (ushort_t*)&sB[0][(w * 64) << 3]);
    gload16(WfT + (size_t)((q0 + 512) >> 2) * 256 + (((q0 + 512) & 3) << 3),
            (ushort_t*)&sB[0][(512 + w * 64) << 3]);

    // ---- epilogue 1: + bo + resid(hb bf16), partial row-sums
    {
      const float bo0 = bo[c0], bo1 = bo[c1];
#pragma unroll
      for (int m = 0; m < 2; ++m)
#pragma unroll
        for (int i = 0; i < 4; ++i) {
          const int rl = m * 16 + l4 * 4 + i;
          const size_t r = (size_t)(m0 + rl);
          float x0 = acc[m][0][i] + bo0 + b2f(hb[r * 256 + c0]);
          float x1 = acc[m][1][i] + bo1 + b2f(hb[r * 256 + c1]);
          acc[m][0][i] = x0; acc[m][1][i] = x1;
          float s = x0 + x1, ss = x0 * x0 + x1 * x1;
          s += __shfl_xor(s, 1, 64); ss += __shfl_xor(ss, 1, 64);
          s += __shfl_xor(s, 2, 64); ss += __shfl_xor(ss, 2, 64);
          s += __shfl_xor(s, 4, 64); ss += __shfl_xor(ss, 4, 64);
          s += __shfl_xor(s, 8, 64); ss += __shfl_xor(ss, 8, 64);
          if (l15 == 0) { pS[w][rl] = s; pSS[w][rl] = ss; }
        }
    }
    __syncthreads();
    // ---- LN -> sH (swizzled, ld 256)
    {
      const float g0 = lg[c0], g1 = lg[c1];
      const float b0 = lb[c0], b1 = lb[c1];
      const int ch0 = c0 >> 3, ch1 = c1 >> 3;
#pragma unroll
      for (int m = 0; m < 2; ++m)
#pragma unroll
        for (int i = 0; i < 4; ++i) {
          const int rl = m * 16 + l4 * 4 + i;
          float s = 0.f, ss = 0.f;
#pragma unroll
          for (int w2 = 0; w2 < 8; ++w2) { s += pS[w2][rl]; ss += pSS[w2][rl]; }
          float mu = s * (1.f / 256.f);
          float var = ss * (1.f / 256.f) - mu * mu;
          float inv = 1.0f / sqrtf(var + 1e-5f);
          sH[rl * 256 + (((ch0 ^ (rl & 7)) << 3) | (c0 & 7))] =
              f2b(g0 * (acc[m][0][i] - mu) * inv + b0);
          sH[rl * 256 + (((ch1 ^ (rl & 7)) << 3) | (c1 & 7))] =
              f2b(g1 * (acc[m][1][i] - mu) * inv + b1);
        }
    }
    __syncthreads();

    // ---- GEMM2: acc = hln @ WfT^T (K=256, 8 double-buffered phases)
#pragma unroll
    for (int m = 0; m < 2; ++m) {
      acc[m][0] = (f32x4){0.f, 0.f, 0.f, 0.f};
      acc[m][1] = (f32x4){0.f, 0.f, 0.f, 0.f};
    }
    for (int ks = 0; ks < 8; ++ks) {
      if (ks < 7) {
        const int k0n = (ks + 1) * 32;
        ushort_t* db = (ushort_t*)sB[(ks + 1) & 1];
        gload16(WfT + (size_t)(q0 >> 2) * 256 + k0n + ((q0 & 3) << 3),
                db + ((w * 64) << 3));
        gload16(WfT + (size_t)((q0 + 512) >> 2) * 256 + k0n + (((q0 + 512) & 3) << 3),
                db + ((512 + w * 64) << 3));
      }
      const ushort_t* bbuf = sB[ks & 1];
      const int ch = ((ks * 32) >> 3) + l4;
      bfrag a0 = *(const bfrag*)(sH + l15 * 256 + ((ch ^ r7) << 3));
      bfrag a1 = *(const bfrag*)(sH + (16 + l15) * 256 + ((ch ^ r7) << 3));
      bfrag b0 = *(const bfrag*)(bbuf + ((c0 * 4 + l4) << 3));
      bfrag b1 = *(const bfrag*)(bbuf + ((c1 * 4 + l4) << 3));
      __builtin_amdgcn_s_setprio(1);
      acc[0][0] = MFMA16(a0, b0, acc[0][0]);
      acc[0][1] = MFMA16(a0, b1, acc[0][1]);
      acc[1][0] = MFMA16(a1, b0, acc[1][0]);
      acc[1][1] = MFMA16(a1, b1, acc[1][1]);
      __builtin_amdgcn_s_setprio(0);
      __syncthreads();
    }

    // ---- issue GEMM3 B-stage (nb=0, kp=0) into sB[0]: K-major [kc][c]
    gload16(W3T + (size_t)(q0 & 127) * 256 + ((q0 >> 7) << 3),
            (ushort_t*)&sB[0][(w * 64) << 3]);
    gload16(W3T + (size_t)((q0 + 512) & 127) * 256 + (((q0 + 512) >> 7) << 3),
            (ushort_t*)&sB[0][(512 + w * 64) << 3]);

    // ---- epilogue 2: gelu -> hb bf16 + sHg (sA, ld 256, swizzled)
    {
      const float bf0 = bfc[c0], bf1 = bfc[c1];
      const int ch0 = c0 >> 3, ch1 = c1 >> 3;
#pragma unroll
      for (int m = 0; m < 2; ++m)
#pragma unroll
        for (int i = 0; i < 4; ++i) {
          const int rl = m * 16 + l4 * 4 + i;
          const size_t r = (size_t)(m0 + rl);
          float x0 = acc[m][0][i] + bf0;
          float x1 = acc[m][1][i] + bf1;
          float t0 = tanhf(0.7978845608028654f * (x0 + 0.044715f * x0 * x0 * x0));
          float t1 = tanhf(0.7978845608028654f * (x1 + 0.044715f * x1 * x1 * x1));
          float gl0 = 0.5f * x0 * (1.f + t0);
          float gl1 = 0.5f * x1 * (1.f + t1);
          ushort_t u0 = f2b(gl0), u1 = f2b(gl1);
          hb[r * 256 + c0] = u0;
          hb[r * 256 + c1] = u1;
          sA[rl * 256 + (((ch0 ^ (rl & 7)) << 3) | (c0 & 7))] = u0;
          sA[rl * 256 + (((ch1 ^ (rl & 7)) << 3) | (c1 & 7))] = u1;
        }
    }
    __syncthreads();
  } else {
    // MODE 2: issue GEMM3 B-stage, then stage h_bf tile -> sHg (sA, swizzled)
    gload16(W3T + (size_t)(q0 & 127) * 256 + ((q0 >> 7) << 3),
            (ushort_t*)&sB[0][(w * 64) << 3]);
    gload16(W3T + (size_t)((q0 + 512) & 127) * 256 + (((q0 + 512) >> 7) << 3),
            (ushort_t*)&sB[0][(512 + w * 64) << 3]);
    for (int i = tid; i < 32 * 32; i += 512) {
      int r = i >> 5, c8 = i & 31;
      *(uint4*)(&sA[r * 256 + ((c8 ^ (r & 7)) << 3)]) =
          *(const uint4*)(A0 + (size_t)(m0 + r) * 256 + c8 * 8);
    }
    __syncthreads();
  }

  // ---- GEMM3: g @ W3T^T. Phases = (panel nb, k-quarter kp); 64 K per phase.
  {
    const int NPH = (MODE == 1) ? 4 : 20;
    const int cl = w * 16 + l15;           // local col in panel
    f32x4 a3[2];
    a3[0] = (f32x4){0.f, 0.f, 0.f, 0.f};
    a3[1] = (f32x4){0.f, 0.f, 0.f, 0.f};
    for (int p = 0; p < NPH; ++p) {
      if (p + 1 < NPH) {
        const int nb2 = (p + 1) >> 2, kp2 = (p + 1) & 3;
        ushort_t* db = (ushort_t*)sB[(p + 1) & 1];
        gload16(W3T + (size_t)(nb2 * 128 + (q0 & 127)) * 256 + kp2 * 64 + ((q0 >> 7) << 3),
                db + ((w * 64) << 3));
        gload16(W3T + (size_t)(nb2 * 128 + ((q0 + 512) & 127)) * 256 + kp2 * 64
                    + (((q0 + 512) >> 7) << 3),
                db + ((512 + w * 64) << 3));
      }
      const ushort_t* bbuf = sB[p & 1];
      const int kp = p & 3;
#pragma unroll
      for (int t = 0; t < 2; ++t) {
        const int kg = kp * 64 + t * 32;
        const int ch = (kg >> 3) + l4;
        bfrag a0 = *(const bfrag*)(sA + l15 * 256 + ((ch ^ r7) << 3));
        bfrag a1 = *(const bfrag*)(sA + (16 + l15) * 256 + ((ch ^ r7) << 3));
        bfrag b0 = *(const bfrag*)(bbuf + (((t * 4 + l4) * 128 + cl) << 3));
        __builtin_amdgcn_s_setprio(1);
        a3[0] = MFMA16(a0, b0, a3[0]);
        a3[1] = MFMA16(a1, b0, a3[1]);
        __builtin_amdgcn_s_setprio(0);
      }
      if (kp == 3) {
        const int c = (p >> 2) * 128 + cl;
#pragma unroll
        for (int m = 0; m < 2; ++m)
#pragma unroll
          for (int i = 0; i < 4; ++i) {
            const size_t r = (size_t)(m0 + m * 16 + l4 * 4 + i);
            float v = a3[m][i];
            if constexpr (MODE == 1) {
              if (c < 103) outF[r * 103 + c] = v + b3[c];
            } else {
              if (c < 328) qext_b[r * 352 + c] = f2b(v);
              else if (c < 584) kvb[r * 256 + (c - 328)] = f2b(v);
            }
            a3[m][i] = 0.f;
          }
      }
      __syncthreads();
    }
  }
}

// ---------------------------------------------------------------------------
// Attention: K/V straight from L2 (XCD-colocated with qkv writer), all LDS
// per-wave, no block barriers. 1024 blocks x 256 threads; wave = 4 points.
__global__ __launch_bounds__(256) void attn_kernel(
    const ushort_t* __restrict__ qext, const ushort_t* __restrict__ kvb,
    const float* __restrict__ pos, const int* __restrict__ nbrs,
    const float* __restrict__ mask, ushort_t* __restrict__ Amsg)
{
  __shared__ __align__(16) ushort_t sQ[4][128];
  __shared__ __align__(16) float    sQE[4][4][52];
  __shared__ __align__(16) ushort_t sRbf[4][16][52];
  __shared__ float sA[4][64];
  __shared__ float sD[4][16];
  __shared__ float sMk[4][16];
  __shared__ int   sNb[4][16];

  const int tid = threadIdx.x;
  const int bid = blockIdx.x;
  const int lane = tid & 63, w = tid >> 6;
  const int g = (bid & 7) + 8 * ((bid >> 3) & 15);
  const int q4 = bid >> 7;
  const int kk = lane >> 2, hh = lane & 3;

  for (int it = 0; it < 4; ++it) {
    const int n = g * 128 + q4 * 16 + w * 4 + it;
    if (lane < 16) {
      int nb = nbrs[n * 16 + lane];
      sNb[w][lane] = nb;
      sMk[w][lane] = mask[n * 16 + lane];
      float dx = pos[nb * 3 + 0] - pos[n * 3 + 0];
      float dy = pos[nb * 3 + 1] - pos[n * 3 + 1];
      float dz = pos[nb * 3 + 2] - pos[n * 3 + 2];
      sD[w][lane] = sqrtf(dx * dx + dy * dy + dz * dz + 1e-12f);
      sRbf[w][lane][50] = 0; sRbf[w][lane][51] = 0;
      *(uint4*)(&sQ[w][lane * 8]) = *(const uint4*)(qext + (size_t)n * 352 + lane * 8);
    }
    if (lane < 50) {
      uint2 u = *(const uint2*)(qext + (size_t)n * 352 + 128 + lane * 4);
      int p = lane * 4;
#pragma unroll
      for (int e = 0; e < 4; ++e) {
        ushort_t bb = ((const ushort_t*)&u)[e];
        int pp = p + e, h2 = pp / 50, r = pp - h2 * 50;
        sQE[w][h2][r] = b2f(bb);
      }
    }
    if (lane < 8) sQE[w][lane >> 1][50 + (lane & 1)] = 0.f;
    {
      int kk2 = lane & 15;
      float dk = sD[w][kk2];
      int r0 = lane >> 4;
#pragma unroll
      for (int j = 0; j < 13; ++j) {
        int r = r0 + j * 4;
        if (r < 50) {
          float t = (dk - (2.f / 49.f) * (float)r) * 24.5f;
          sRbf[w][kk2][r] = f2b(__expf(-0.5f * t * t));
        }
      }
    }
    const int nb = sNb[w][kk];
    const ushort_t* krow = kvb + (size_t)nb * 256 + hh * 32;
    float qk = 0.f;
#pragma unroll
    for (int c8 = 0; c8 < 4; ++c8) {
      uint4 kv4 = *(const uint4*)(krow + c8 * 8);
      const uint_t* q4p = (const uint_t*)(&sQ[w][hh * 32 + c8 * 8]);
      uint_t qa = q4p[0], qb = q4p[1], qc = q4p[2], qd = q4p[3];
      qk += blo(qa) * blo(kv4.x) + bhi(qa) * bhi(kv4.x)
          + blo(qb) * blo(kv4.y) + bhi(qb) * bhi(kv4.y)
          + blo(qc) * blo(kv4.z) + bhi(qc) * bhi(kv4.z)
          + blo(qd) * blo(kv4.w) + bhi(qd) * bhi(kv4.w);
    }
    float qe = 0.f;
#pragma unroll
    for (int c = 0; c < 13; ++c) {
      float4 qv = *(const float4*)(&sQE[w][hh][c * 4]);
      uint2 rv = *(const uint2*)(&sRbf[w][kk][c * 4]);
      qe += qv.x * blo(rv.x) + qv.y * bhi(rv.x)
          + qv.z * blo(rv.y) + qv.w * bhi(rv.y);
    }
    float lg = 0.17677669529663687f * (qk + qe);
    lg = (sMk[w][kk] > 0.f) ? lg : -1e9f;

    float mx = lg;
#pragma unroll
    for (int off = 4; off < 64; off <<= 1) mx = fmaxf(mx, __shfl_xor(mx, off, 64));
    float ex = __expf(lg - mx);
    float sm = ex;
#pragma unroll
    for (int off = 4; off < 64; off <<= 1) sm += __shfl_xor(sm, off, 64);
    sA[w][kk * 4 + hh] = ex / sm * sMk[w][kk];

    if (lane < 50) {
      float r0 = 0.f, r1 = 0.f, r2 = 0.f, r3 = 0.f;
#pragma unroll
      for (int k2 = 0; k2 < 16; ++k2) {
        float rb = b2f(sRbf[w][k2][lane]);
        r0 += sA[w][k2 * 4 + 0] * rb;
        r1 += sA[w][k2 * 4 + 1] * rb;
        r2 += sA[w][k2 * 4 + 2] * rb;
        r3 += sA[w][k2 * 4 + 3] * rb;
      }
      Amsg[(size_t)n * 352 + 128 + 0 * 50 + lane] = f2b(r0);
      Amsg[(size_t)n * 352 + 128 + 1 * 50 + lane] = f2b(r1);
      Amsg[(size_t)n * 352 + 128 + 2 * 50 + lane] = f2b(r2);
      Amsg[(size_t)n * 352 + 128 + 3 * 50 + lane] = f2b(r3);
    }
    {
      const int h2 = lane >> 4;
      float m0v = 0.f, m1v = 0.f;
#pragma unroll
      for (int k2 = 0; k2 < 16; ++k2) {
        int nb2 = sNb[w][k2];
        uint_t vv = *(const uint_t*)(kvb + (size_t)nb2 * 256 + 128 + lane * 2);
        float a = sA[w][k2 * 4 + h2];
        m0v += a * blo(vv);
        m1v += a * bhi(vv);
      }
      uint_t o = (uint_t)f2b(m0v) | ((uint_t)f2b(m1v) << 16);
      *(uint_t*)(&Amsg[(size_t)n * 352 + lane * 2]) = o;
    }
    if (lane < 24) Amsg[(size_t)n * 352 + 328 + lane] = 0;
  }
}

// ---------------------------------------------------------------------------
extern "C" void kernel_launch(void* const* d_in, const int* in_sizes, int n_in,
                              void* d_out, int out_size, void* d_ws, size_t ws_size,
                              hipStream_t stream) {
  const float* enc    = (const float*)d_in[0];
  const float* pos    = (const float*)d_in[1];
  const int*   bidx   = (const int*)  d_in[2];
  const int*   nbrs   = (const int*)  d_in[3];
  const float* mask   = (const float*)d_in[4];
  const float* W_in   = (const float*)d_in[5];
  const float* b_in   = (const float*)d_in[6];
  const float* Wq     = (const float*)d_in[7];
  const float* Wk     = (const float*)d_in[8];
  const float* Wv     = (const float*)d_in[9];
  const float* We     = (const float*)d_in[10];
  const float* Wo     = (const float*)d_in[11];
  const float* bo     = (const float*)d_in[12];
  const float* Wfc    = (const float*)d_in[13];
  const float* bfc    = (const float*)d_in[14];
  const float* ln_g   = (const float*)d_in[15];
  const float* ln_b   = (const float*)d_in[16];
  const float* W_out  = (const float*)d_in[17];
  const float* b_out  = (const float*)d_in[18];
  float* out = (float*)d_out;

  const int N = N_PTS;
  ushort_t* ws = (ushort_t*)d_ws;
  ushort_t* hb     = ws;                                  // N*256 bf16 residual
  ushort_t* qext_b = hb + (size_t)N * 256;                // N*352 bf16
  ushort_t* kvb    = qext_b + (size_t)N * 352;            // N*256 bf16
  ushort_t* Amsg   = kvb + (size_t)N * 256;               // N*352 bf16
  float*    base   = (float*)(Amsg + (size_t)N * 352);    // 128*256 fp32
  ushort_t* WqkvT  = (ushort_t*)(base + 128 * 256);       // 4*640*256
  ushort_t* BcT    = WqkvT + 4 * 640 * 256;               // 4*256*384
  ushort_t* WfT    = BcT  + 4 * 256 * 384;                // 4*256*256
  ushort_t* WoT    = WfT  + 4 * 256 * 256;                // 128*256

  base_kernel<<<128, 256, 0, stream>>>(enc, W_in, b_in, base);
  embed_kernel<<<N, 256, 0, stream>>>(base, bidx, pos, W_in, hb);
  prep_qkv<<<(4 * 640 * 256) / 256, 256, 0, stream>>>(Wq, Wk, Wv, We, WqkvT);
  prep_bcat<<<(4 * 256 * 384) / 256, 256, 0, stream>>>(We, Wo, BcT);
  prep_wfc<<<(4 * 256 * 256) / 256, 256, 0, stream>>>(Wfc, WfT);
  prep_wout<<<(128 * 256) / 256, 256, 0, stream>>>(W_out, WoT);

  // layer-0 qkv from embedded features
  fused_layer<2><<<N / 32, 512, 0, stream>>>(
      hb, nullptr, nullptr, nullptr, nullptr, nullptr, nullptr, nullptr,
      WqkvT, nullptr, qext_b, kvb, nullptr);

  for (int l = 0; l < NLAYER; ++l) {
    const ushort_t* BcT_l = BcT + (size_t)l * 256 * 384;
    const ushort_t* WfT_l = WfT + (size_t)l * 256 * 256;
    const float* bo_l  = bo  + (size_t)l * 256;
    const float* bfc_l = bfc + (size_t)l * 256;
    const float* lg_l  = ln_g + (size_t)l * 256;
    const float* lb_l  = ln_b + (size_t)l * 256;

    attn_kernel<<<1024, 256, 0, stream>>>(qext_b, kvb, pos, nbrs, mask, Amsg);

    if (l < NLAYER - 1) {
      const ushort_t* Wqkv_next = WqkvT + (size_t)(l + 1) * 640 * 256;
      fused_layer<0><<<N / 32, 512, 0, stream>>>(
          Amsg, BcT_l, bo_l, hb, lg_l, lb_l, WfT_l, bfc_l,
          Wqkv_next, nullptr, qext_b, kvb, nullptr);
    } else {
      fused_layer<1><<<N / 32, 512, 0, stream>>>(
          Amsg, BcT_l, bo_l, hb, lg_l, lb_l, WfT_l, bfc_l,
          WoT, b_out, nullptr, nullptr, out);
    }
  }
}